// Round 2
// baseline (457.250 us; speedup 1.0000x reference)
//
#include <hip/hip_runtime.h>
#include <stdint.h>

// Problem constants (fixed for this instance)
#define IN_C   128
#define HID_C  128
#define NREL   8
#define K_TOTAL (NREL * IN_C)   // 1024
#define TILE_M  16              // nodes per tile
#define SRB     1032            // bf16 units per node row in LDS (1024 + 8 pad)
#define GEMM_GRID 768           // persistent-ish blocks (3 per CU)

typedef float  f32x4  __attribute__((ext_vector_type(4)));
typedef __bf16 bf16x8 __attribute__((ext_vector_type(8)));
typedef short  s16x8  __attribute__((ext_vector_type(8)));
typedef unsigned short u16;

__device__ __forceinline__ unsigned short f2bf(float f) {
    unsigned int u = __float_as_uint(f);
    u += 0x7fffu + ((u >> 16) & 1u);   // round-to-nearest-even
    return (unsigned short)(u >> 16);
}

__global__ void zero_count_kernel(unsigned int* count) { *count = 0u; }

// ---------------- prep (fused): compute-node list + W->bf16 transpose
//                  + x->bf16 conversion + history copy
__global__ __launch_bounds__(256) void prep_kernel(
        const float* __restrict__ x, const float* __restrict__ W,
        const int* __restrict__ hmap, const float* __restrict__ hbuf,
        unsigned short* __restrict__ xh, unsigned short* __restrict__ Wt,
        int* __restrict__ list, unsigned int* __restrict__ count,
        float* __restrict__ out, int NN, int WE, int use_xh) {
    int gid = blockIdx.x * blockDim.x + threadIdx.x;

    // compact list of compute nodes (wave-aggregated atomics). No early
    // returns above this point: all lanes must reach the ballot.
    {
        bool active = (gid < NN) && (hmap[gid] == -1);
        unsigned long long mask = __ballot(active);
        if (mask) {
            int lane   = threadIdx.x & 63;
            int leader = __ffsll((unsigned long long)mask) - 1;
            unsigned base = 0;
            if (lane == leader) base = atomicAdd(count, (unsigned)__popcll(mask));
            base = __shfl(base, leader, 64);
            if (active) {
                int off = __popcll(mask & ((1ull << lane) - 1ull));
                list[base + off] = gid;
            }
        }
    }

    // per (node, f32x4-chunk): x -> bf16, and history-row copy
    int n = gid >> 5;           // node
    int q = gid & 31;           // f32x4 index within 128-float row
    if (n < NN) {
        if (use_xh) {
            f32x4 xv = ((const f32x4*)x)[(size_t)n * 32 + q];
            ushort4 pk;
            pk.x = f2bf(xv[0]); pk.y = f2bf(xv[1]);
            pk.z = f2bf(xv[2]); pk.w = f2bf(xv[3]);
            ((ushort4*)xh)[(size_t)n * 32 + q] = pk;   // 8 B store
        }
        if (hmap[n] != -1) {
            f32x4 v = ((const f32x4*)hbuf)[(size_t)n * 32 + q];
            f32x4* o = (f32x4*)out;
            o[(size_t)n * 32 + q] = v;
            o[(size_t)NN * 32 + (size_t)n * 32 + q] = v;
        }
    }

    // W[r][k][c] -> Wt[c][r*128+k] in bf16
    if (gid < WE) {
        int r   = gid >> 14;      // / (128*128)
        int rem = gid & 16383;
        int k   = rem >> 7;       // / 128
        int c   = rem & 127;
        Wt[(size_t)c * K_TOTAL + r * IN_C + k] = f2bf(W[gid]);
    }
}

// ---------------- pipelined persistent gather+GEMM
// Each block loops over tiles (grid stride). Per iteration:
//   phase1: [producer] shfl metas (prefetched last iter), issue 8 edge gathers,
//           prefetch next tile's list/ptr/idx/ety;   [consumer] MFMA + store
//           previous tile from S.
//   barrier (compiler drains vmcnt here -> gathers landed, latency hidden
//   under the MFMA section)
//   phase2: [producer] issue remaining 8 gathers, one-hot accumulate all 16,
//           convert to bf16, write S + per-tile nids/invdeg.
//   barrier
// XBF=1: gather pre-converted bf16 x (16 B/edge/thread); XBF=0: f32 fallback.
template<int XBF>
__global__ __launch_bounds__(256, 3) void gemm_kernel_t(
        const float* __restrict__ x,
        const unsigned short* __restrict__ xh,
        const int* __restrict__ ptr,
        const int* __restrict__ idx,
        const int* __restrict__ ety,
        const unsigned short* __restrict__ Wt,
        const int* __restrict__ list,
        const unsigned int* __restrict__ count,
        float* __restrict__ out, int NN) {
    constexpr int LW = XBF ? 1 : 2;     // uint4 loads per edge per thread
    __shared__ u16   S[TILE_M * SRB];   // 33024 B, bf16 staged A-tile
    __shared__ int   nids_l[TILE_M];
    __shared__ float invd_l[TILE_M];

    unsigned int cnt = *count;
    int ntiles = (int)((cnt + TILE_M - 1) / TILE_M);
    int tile_p = blockIdx.x;
    if (tile_p >= ntiles) return;       // uniform exit, before any barrier

    int t = threadIdx.x;
    int n = t >> 4;            // node slot 0..15
    int c = t & 15;            // 8-channel chunk 0..15
    int lane = t & 63;
    int wave = t >> 6;
    int quad = lane >> 4, l16 = lane & 15;
    int chbase = wave * 32;
    const u16* arow  = S + l16 * SRB + quad * 8;
    const u16* bbase = Wt + (size_t)(chbase + l16) * K_TOTAL + quad * 8;
    const char* xcb = XBF ? ((const char*)xh + c * 16)
                          : ((const char*)x  + c * 32);
    int stride = (int)gridDim.x;

    // stage-1: list/ptr/meta for a tile (3-deep dependent chain; always
    // issued one full iteration before use)
    auto stage1 = [&](int T, int& nid_, int& e0_, int& deg_, unsigned& m_) {
        nid_ = -1; e0_ = 0; deg_ = 0; m_ = 31u << 27;
        if (T < ntiles) {
            int row = T * TILE_M + n;
            if (row < (int)cnt) {
                int nd = list[row];
                nid_ = nd;
                int a = ptr[nd], b2 = ptr[nd + 1];
                e0_ = a; deg_ = b2 - a;
                if (c < deg_) {
                    int e = a + c;
                    m_ = ((unsigned)idx[e]) | (((unsigned)ety[e]) << 27);
                }
            }
        }
    };

    // one-hot accumulators (per thread: 8 relations x 8 channels)
    f32x4 alo[NREL], ahi[NREL];

    auto accum_bf = [&](uint4 v, unsigned m) {
        int r_ = (int)(m >> 27);
        f32x4 lo_, hi_;
        lo_[0] = __uint_as_float(v.x << 16);
        lo_[1] = __uint_as_float(v.x & 0xFFFF0000u);
        lo_[2] = __uint_as_float(v.y << 16);
        lo_[3] = __uint_as_float(v.y & 0xFFFF0000u);
        hi_[0] = __uint_as_float(v.z << 16);
        hi_[1] = __uint_as_float(v.z & 0xFFFF0000u);
        hi_[2] = __uint_as_float(v.w << 16);
        hi_[3] = __uint_as_float(v.w & 0xFFFF0000u);
        #pragma unroll
        for (int rr = 0; rr < NREL; ++rr) {
            float mk = (r_ == rr) ? 1.0f : 0.0f;
            alo[rr] += lo_ * mk;
            ahi[rr] += hi_ * mk;
        }
    };
    auto accum_f32 = [&](uint4 a, uint4 b, unsigned m) {
        int r_ = (int)(m >> 27);
        f32x4 lo_, hi_;
        lo_[0] = __uint_as_float(a.x); lo_[1] = __uint_as_float(a.y);
        lo_[2] = __uint_as_float(a.z); lo_[3] = __uint_as_float(a.w);
        hi_[0] = __uint_as_float(b.x); hi_[1] = __uint_as_float(b.y);
        hi_[2] = __uint_as_float(b.z); hi_[3] = __uint_as_float(b.w);
        #pragma unroll
        for (int rr = 0; rr < NREL; ++rr) {
            float mk = (r_ == rr) ? 1.0f : 0.0f;
            alo[rr] += lo_ * mk;
            ahi[rr] += hi_ * mk;
        }
    };

    int nidP, e0P, degP; unsigned mP;
    stage1(tile_p, nidP, e0P, degP, mP);

    bool haveC = false;

    for (;;) {
        bool haveP = (tile_p < ntiles);
        unsigned mm[16];
        uint4 gA[8 * LW];
        int nidN = -1, e0N = 0, degN = 0; unsigned mN = 31u << 27;

        // ---------------- phase 1: producer issue + consumer MFMA
        if (haveP) {
            stage1(tile_p + stride, nidN, e0N, degN, mN);   // for next iter
            #pragma unroll
            for (int j = 0; j < 16; ++j)
                mm[j] = __shfl(mP, (lane & 48) | j, 64);
            #pragma unroll
            for (int u = 0; u < 8; ++u) {
                const char* p = xcb + ((size_t)(mm[u] & 0x07FFFFFFu) << (XBF ? 8 : 9));
                gA[u * LW] = *(const uint4*)p;
                if (!XBF) gA[u * LW + 1] = *(const uint4*)(p + 16);
            }
        }
        __builtin_amdgcn_sched_barrier(0);   // keep gathers above MFMA

        if (haveC) {
            f32x4 acc0 = {0.f,0.f,0.f,0.f};
            f32x4 acc1 = {0.f,0.f,0.f,0.f};
            #pragma unroll 8
            for (int ks = 0; ks < K_TOTAL; ks += 32) {
                s16x8 a  = *(const s16x8*)(arow + ks);
                s16x8 b0 = *(const s16x8*)(bbase + ks);
                s16x8 b1 = *(const s16x8*)(bbase + ks + 16 * K_TOTAL);
                union { s16x8 s; bf16x8 b; } ua, ub0, ub1;
                ua.s = a; ub0.s = b0; ub1.s = b1;
                acc0 = __builtin_amdgcn_mfma_f32_16x16x32_bf16(ua.b, ub0.b, acc0, 0, 0, 0);
                acc1 = __builtin_amdgcn_mfma_f32_16x16x32_bf16(ua.b, ub1.b, acc1, 0, 0, 0);
            }
            // epilogue: C/D layout col=lane&15, row=(lane>>4)*4+reg
            size_t half = (size_t)NN * HID_C;
            #pragma unroll
            for (int v = 0; v < 4; ++v) {
                int rowl = quad * 4 + v;
                int onid = nids_l[rowl];
                if (onid < 0) continue;
                float s = invd_l[rowl];
                float v0 = acc0[v] * s;
                float v1 = acc1[v] * s;
                size_t o0 = (size_t)onid * HID_C + chbase + l16;
                out[o0]             = v0;
                out[o0 + 16]        = v1;
                out[o0 + half]      = v0;
                out[o0 + 16 + half] = v1;
            }
        }
        __syncthreads();     // S consumed; producer gathers drained here
        if (!haveP) break;

        // ---------------- phase 2: accumulate + write S
        {
            #pragma unroll
            for (int r = 0; r < NREL; ++r) {
                alo[r] = f32x4{0,0,0,0}; ahi[r] = f32x4{0,0,0,0};
            }
            uint4 gB[8 * LW];
            #pragma unroll
            for (int u = 0; u < 8; ++u) {
                const char* p = xcb + ((size_t)(mm[8 + u] & 0x07FFFFFFu) << (XBF ? 8 : 9));
                gB[u * LW] = *(const uint4*)p;
                if (!XBF) gB[u * LW + 1] = *(const uint4*)(p + 16);
            }
            #pragma unroll
            for (int u = 0; u < 8; ++u) {
                if (XBF) accum_bf(gA[u], mm[u]);
                else     accum_f32(gA[u * 2], gA[u * 2 + 1], mm[u]);
            }
            #pragma unroll
            for (int u = 0; u < 8; ++u) {
                if (XBF) accum_bf(gB[u], mm[8 + u]);
                else     accum_f32(gB[u * 2], gB[u * 2 + 1], mm[8 + u]);
            }

            // rare general path: deg > 16 (wave-uniform trip count for shfl)
            int md = degP;
            #pragma unroll
            for (int off = 1; off <= 32; off <<= 1)
                md = max(md, __shfl_xor(md, off, 64));
            for (int jb = 16; jb < md; jb += 16) {
                unsigned m2 = 31u << 27;
                if (nidP >= 0 && jb + c < degP) {
                    int e = e0P + jb + c;
                    m2 = ((unsigned)idx[e]) | (((unsigned)ety[e]) << 27);
                }
                #pragma unroll
                for (int j = 0; j < 16; ++j) {
                    unsigned mx = __shfl(m2, (lane & 48) | j, 64);
                    const char* p = xcb + ((size_t)(mx & 0x07FFFFFFu) << (XBF ? 8 : 9));
                    if (XBF) {
                        uint4 g = *(const uint4*)p;
                        accum_bf(g, mx);
                    } else {
                        uint4 g0 = *(const uint4*)p;
                        uint4 g1 = *(const uint4*)(p + 16);
                        accum_f32(g0, g1, mx);
                    }
                }
            }

            // convert once to bf16, write S tile
            u16* srow = S + n * SRB + c * 8;
            #pragma unroll
            for (int rr = 0; rr < NREL; ++rr) {
                s16x8 pk;
                pk[0] = (short)f2bf(alo[rr][0]); pk[1] = (short)f2bf(alo[rr][1]);
                pk[2] = (short)f2bf(alo[rr][2]); pk[3] = (short)f2bf(alo[rr][3]);
                pk[4] = (short)f2bf(ahi[rr][0]); pk[5] = (short)f2bf(ahi[rr][1]);
                pk[6] = (short)f2bf(ahi[rr][2]); pk[7] = (short)f2bf(ahi[rr][3]);
                *(s16x8*)(srow + rr * IN_C) = pk;
            }
            if (c == 0) {
                nids_l[n] = nidP;
                invd_l[n] = (degP > 0) ? 1.0f / (float)degP : 0.f;
            }
        }
        __syncthreads();     // S(tile_p) + nids ready for next iteration

        haveC = true;
        tile_p += stride;
        nidP = nidN; e0P = e0N; degP = degN; mP = mN;
    }
}

extern "C" void kernel_launch(void* const* d_in, const int* in_sizes, int n_in,
                              void* d_out, int out_size, void* d_ws, size_t ws_size,
                              hipStream_t stream) {
    const float* x    = (const float*)d_in[0];
    const float* W    = (const float*)d_in[1];
    const int*   ptr  = (const int*)d_in[2];
    const int*   idx  = (const int*)d_in[3];
    const int*   ety  = (const int*)d_in[4];
    const int*   hmap = (const int*)d_in[5];
    const float* hbuf = (const float*)d_in[6];
    int NN = in_sizes[5];          // 100000
    int WE = in_sizes[1];          // 8*128*128
    float* out = (float*)d_out;

    // workspace layout: count | list | Wt(bf16) | xh(bf16 x)
    unsigned int* count = (unsigned int*)d_ws;
    int* list = (int*)((char*)d_ws + 256);
    size_t wt_off = 256 + (((size_t)NN * 4 + 4095) / 4096) * 4096;
    unsigned short* Wt = (unsigned short*)((char*)d_ws + wt_off);      // 256 KB
    size_t xh_off = ((wt_off + (size_t)K_TOTAL * HID_C * 2 + 4095) / 4096) * 4096;
    unsigned short* xh = (unsigned short*)((char*)d_ws + xh_off);      // NN*128*2 B
    size_t need = xh_off + (size_t)NN * IN_C * 2;
    int use_xh = (ws_size >= need) ? 1 : 0;

    zero_count_kernel<<<1, 1, 0, stream>>>(count);

    long long tot = (long long)NN * 32;           // covers x-conv + history
    if (tot < (long long)WE) tot = WE;
    prep_kernel<<<(int)((tot + 255) / 256), 256, 0, stream>>>(
        x, W, hmap, hbuf, xh, Wt, list, count, out, NN, WE, use_xh);

    if (use_xh) {
        gemm_kernel_t<1><<<GEMM_GRID, 256, 0, stream>>>(
            x, xh, ptr, idx, ety, Wt, list, count, out, NN);
    } else {
        gemm_kernel_t<0><<<GEMM_GRID, 256, 0, stream>>>(
            x, xh, ptr, idx, ety, Wt, list, count, out, NN);
    }
}

// Round 3
// 303.035 us; speedup vs baseline: 1.5089x; 1.5089x over previous
//
#include <hip/hip_runtime.h>
#include <stdint.h>

// Problem constants (fixed for this instance)
#define IN_C   128
#define HID_C  128
#define NREL   8
#define K_TOTAL (NREL * IN_C)   // 1024
#define TILE_M  16              // nodes per block
#define SRB     1032            // bf16 units per node row in LDS (1024 + 8 pad)

typedef float  f32x4  __attribute__((ext_vector_type(4)));
typedef __bf16 bf16x8 __attribute__((ext_vector_type(8)));
typedef short  s16x8  __attribute__((ext_vector_type(8)));
typedef unsigned short u16;

__device__ __forceinline__ unsigned short f2bf(float f) {
    unsigned int u = __float_as_uint(f);
    u += 0x7fffu + ((u >> 16) & 1u);   // round-to-nearest-even
    return (unsigned short)(u >> 16);
}

__global__ void zero_count_kernel(unsigned int* count) { *count = 0u; }

// ---------------- prep (fused): compute-node list + W->bf16 transpose
//                  + history copy
__global__ __launch_bounds__(256) void prep_kernel(
        const float* __restrict__ W,
        const int* __restrict__ hmap, const float* __restrict__ hbuf,
        unsigned short* __restrict__ Wt,
        int* __restrict__ list, unsigned int* __restrict__ count,
        float* __restrict__ out, int NN, int WE) {
    int gid = blockIdx.x * blockDim.x + threadIdx.x;

    // compact list of compute nodes (wave-aggregated atomics). No early
    // returns above this point: all lanes must reach the ballot.
    {
        bool active = (gid < NN) && (hmap[gid] == -1);
        unsigned long long mask = __ballot(active);
        if (mask) {
            int lane   = threadIdx.x & 63;
            int leader = __ffsll((unsigned long long)mask) - 1;
            unsigned base = 0;
            if (lane == leader) base = atomicAdd(count, (unsigned)__popcll(mask));
            base = __shfl(base, leader, 64);
            if (active) {
                int off = __popcll(mask & ((1ull << lane) - 1ull));
                list[base + off] = gid;
            }
        }
    }

    // per (node, f32x4-chunk): history-row copy to both output halves
    int n = gid >> 5;           // node
    int q = gid & 31;           // f32x4 index within 128-float row
    if (n < NN) {
        if (hmap[n] != -1) {
            f32x4 v = ((const f32x4*)hbuf)[(size_t)n * 32 + q];
            f32x4* o = (f32x4*)out;
            o[(size_t)n * 32 + q] = v;
            o[(size_t)NN * 32 + (size_t)n * 32 + q] = v;
        }
    }

    // W[r][k][c] -> Wt[c][r*128+k] in bf16
    if (gid < WE) {
        int r   = gid >> 14;      // / (128*128)
        int rem = gid & 16383;
        int k   = rem >> 7;       // / 128
        int c   = rem & 127;
        Wt[(size_t)c * K_TOTAL + r * IN_C + k] = f2bf(W[gid]);
    }
}

// ---------------- fused gather (pipelined, branch-free) + bf16 MFMA GEMM
// R0-proven structure; only change: min 4 blocks/CU (was 3).
__global__ __launch_bounds__(256, 4) void gemm_kernel(
        const float* __restrict__ x,
        const int* __restrict__ ptr,
        const int* __restrict__ idx,
        const int* __restrict__ ety,
        const unsigned short* __restrict__ Wt,
        const int* __restrict__ list,
        const unsigned int* __restrict__ count,
        float* __restrict__ out, int NN) {
    __shared__ u16      S[TILE_M * SRB];      // 33024 B, bf16 staged A-tile
    __shared__ unsigned meta[TILE_M * 16];    // packed src | rel<<27
    __shared__ int      nids[TILE_M];
    __shared__ int      degs[TILE_M];
    __shared__ float    invdeg[TILE_M];

    unsigned int cnt = *count;
    int rowbase = blockIdx.x * TILE_M;
    if (rowbase >= (int)cnt) return;          // uniform exit, before any barrier

    int t = threadIdx.x;
    if (t < TILE_M) {
        int row = rowbase + t;
        int nid = -1, d = 0; float idg = 0.f;
        if (row < (int)cnt) {
            nid = list[row];
            int e0 = ptr[nid], e1 = ptr[nid + 1];
            d = e1 - e0;
            idg = (d > 0) ? 1.0f / (float)d : 0.f;
        }
        nids[t] = nid; degs[t] = d; invdeg[t] = idg;
    }
    __syncthreads();

    int n = t >> 4;            // node slot 0..15
    int c = t & 15;            // 8-float channel chunk 0..15
    int nid = nids[n];
    int deg = degs[n];
    int e0  = (nid >= 0) ? ptr[nid] : 0;

    int maxdeg = 0;
    #pragma unroll
    for (int i = 0; i < TILE_M; ++i) maxdeg = max(maxdeg, degs[i]);

    // per-thread accumulator: 8 relations x 8 channels (64 VGPRs)
    f32x4 alo[NREL], ahi[NREL];
    #pragma unroll
    for (int r = 0; r < NREL; ++r) { alo[r] = f32x4{0,0,0,0}; ahi[r] = f32x4{0,0,0,0}; }

    const float* xc = x + c * 8;   // channel-chunk base

    for (int jb = 0; jb < maxdeg; jb += 16) {
        // stage this 16-edge chunk's meta, coalesced
        {
            int j = jb + c;
            unsigned m = 0xFFFFFFFFu;
            if (nid >= 0 && j < deg) {
                int e = e0 + j;
                m = ((unsigned)idx[e]) | (((unsigned)ety[e]) << 27);
            }
            meta[t] = m;
        }
        __syncthreads();

        // pull all 16 metas into registers (4 x ds_read_b128), decode branch-free
        unsigned mm[16];
        {
            uint4 q0 = *(const uint4*)(meta + (n << 4) + 0);
            uint4 q1 = *(const uint4*)(meta + (n << 4) + 4);
            uint4 q2 = *(const uint4*)(meta + (n << 4) + 8);
            uint4 q3 = *(const uint4*)(meta + (n << 4) + 12);
            mm[0]=q0.x;  mm[1]=q0.y;  mm[2]=q0.z;  mm[3]=q0.w;
            mm[4]=q1.x;  mm[5]=q1.y;  mm[6]=q1.z;  mm[7]=q1.w;
            mm[8]=q2.x;  mm[9]=q2.y;  mm[10]=q2.z; mm[11]=q2.w;
            mm[12]=q3.x; mm[13]=q3.y; mm[14]=q3.z; mm[15]=q3.w;
        }
        int offs[16];   // element offset of this thread's chunk in x
        int rel[16];    // relation id, 31 = inactive (one-hot never matches)
        #pragma unroll
        for (int j = 0; j < 16; ++j) {
            unsigned m = mm[j];
            bool valid = (m != 0xFFFFFFFFu);
            int src = valid ? (int)(m & 0x07FFFFFFu) : 0;
            rel[j]  = valid ? (int)(m >> 27) : 31;
            offs[j] = src * IN_C;
        }

        // software pipeline: 4-edge batches, double-buffered (8 edges in flight)
        f32x4 blo[4], bhi[4];
        #pragma unroll
        for (int u = 0; u < 4; ++u) {
            const f32x4* p = (const f32x4*)(xc + offs[u]);
            blo[u] = p[0]; bhi[u] = p[1];
        }
        #pragma unroll
        for (int b = 0; b < 4; ++b) {
            f32x4 nlo[4], nhi[4];
            if (b < 3) {
                #pragma unroll
                for (int u = 0; u < 4; ++u) {
                    const f32x4* p = (const f32x4*)(xc + offs[(b + 1) * 4 + u]);
                    nlo[u] = p[0]; nhi[u] = p[1];
                }
            }
            #pragma unroll
            for (int u = 0; u < 4; ++u) {
                int r = rel[b * 4 + u];
                #pragma unroll
                for (int rr = 0; rr < NREL; ++rr) {       // branchless one-hot
                    float mk = (r == rr) ? 1.0f : 0.0f;
                    alo[rr] += blo[u] * mk;
                    ahi[rr] += bhi[u] * mk;
                }
            }
            if (b < 3) {
                #pragma unroll
                for (int u = 0; u < 4; ++u) { blo[u] = nlo[u]; bhi[u] = nhi[u]; }
            }
        }
        __syncthreads();   // meta reuse fence for next chunk
    }

    // convert once to bf16, write S tile (write-once, no zeroing needed)
    {
        u16* srow = S + n * SRB + c * 8;
        #pragma unroll
        for (int rr = 0; rr < NREL; ++rr) {
            s16x8 pk;
            pk[0] = (short)f2bf(alo[rr][0]); pk[1] = (short)f2bf(alo[rr][1]);
            pk[2] = (short)f2bf(alo[rr][2]); pk[3] = (short)f2bf(alo[rr][3]);
            pk[4] = (short)f2bf(ahi[rr][0]); pk[5] = (short)f2bf(ahi[rr][1]);
            pk[6] = (short)f2bf(ahi[rr][2]); pk[7] = (short)f2bf(ahi[rr][3]);
            *(s16x8*)(srow + rr * IN_C) = pk;
        }
    }
    __syncthreads();

    // MFMA over K=1024
    int wave = t >> 6, lane = t & 63;
    int quad = lane >> 4, l16 = lane & 15;
    int chbase = wave * 32;                 // each wave owns 32 output channels
    const u16* arow  = S + l16 * SRB + quad * 8;
    const u16* bbase = Wt + (size_t)(chbase + l16) * K_TOTAL + quad * 8;

    f32x4 acc0 = {0.f,0.f,0.f,0.f};
    f32x4 acc1 = {0.f,0.f,0.f,0.f};
    #pragma unroll 8
    for (int ks = 0; ks < K_TOTAL; ks += 32) {
        s16x8 a  = *(const s16x8*)(arow + ks);
        s16x8 b0 = *(const s16x8*)(bbase + ks);
        s16x8 b1 = *(const s16x8*)(bbase + ks + 16 * K_TOTAL);
        union { s16x8 s; bf16x8 b; } ua, ub0, ub1;
        ua.s = a; ub0.s = b0; ub1.s = b1;
        acc0 = __builtin_amdgcn_mfma_f32_16x16x32_bf16(ua.b, ub0.b, acc0, 0, 0, 0);
        acc1 = __builtin_amdgcn_mfma_f32_16x16x32_bf16(ua.b, ub1.b, acc1, 0, 0, 0);
    }

    // epilogue: C/D layout col=lane&15, row=(lane>>4)*4+reg  (verified)
    size_t half = (size_t)NN * HID_C;
    #pragma unroll
    for (int v = 0; v < 4; ++v) {
        int rowl = quad * 4 + v;
        int onid = nids[rowl];
        if (onid < 0) continue;
        float s = invdeg[rowl];
        float v0 = acc0[v] * s;
        float v1 = acc1[v] * s;
        size_t o0 = (size_t)onid * HID_C + chbase + l16;
        out[o0]             = v0;
        out[o0 + 16]        = v1;
        out[o0 + half]      = v0;
        out[o0 + 16 + half] = v1;
    }
}

extern "C" void kernel_launch(void* const* d_in, const int* in_sizes, int n_in,
                              void* d_out, int out_size, void* d_ws, size_t ws_size,
                              hipStream_t stream) {
    const float* x    = (const float*)d_in[0];
    const float* W    = (const float*)d_in[1];
    const int*   ptr  = (const int*)d_in[2];
    const int*   idx  = (const int*)d_in[3];
    const int*   ety  = (const int*)d_in[4];
    const int*   hmap = (const int*)d_in[5];
    const float* hbuf = (const float*)d_in[6];
    int NN = in_sizes[5];          // 100000
    int WE = in_sizes[1];          // 8*128*128
    float* out = (float*)d_out;

    // workspace layout: count | list | Wt(bf16)
    unsigned int* count = (unsigned int*)d_ws;
    int* list = (int*)((char*)d_ws + 256);
    size_t wt_off = 256 + (((size_t)NN * 4 + 4095) / 4096) * 4096;
    unsigned short* Wt = (unsigned short*)((char*)d_ws + wt_off);      // 256 KB

    zero_count_kernel<<<1, 1, 0, stream>>>(count);

    long long tot = (long long)NN * 32;           // covers history copy
    if (tot < (long long)WE) tot = WE;
    prep_kernel<<<(int)((tot + 255) / 256), 256, 0, stream>>>(
        W, hmap, hbuf, Wt, list, count, out, NN, WE);

    gemm_kernel<<<(NN + TILE_M - 1) / TILE_M, 256, 0, stream>>>(
        x, ptr, idx, ety, Wt, list, count, out, NN);
}

// Round 4
// 302.776 us; speedup vs baseline: 1.5102x; 1.0009x over previous
//
#include <hip/hip_runtime.h>
#include <stdint.h>

// Problem constants (fixed for this instance)
#define IN_C   128
#define HID_C  128
#define NREL   8
#define K_TOTAL (NREL * IN_C)   // 1024
#define TILE_M  16              // nodes per block
#define SRB     1032            // bf16 units per node row in LDS (1024 + 8 pad)

typedef float  f32x4  __attribute__((ext_vector_type(4)));
typedef __bf16 bf16x8 __attribute__((ext_vector_type(8)));
typedef short  s16x8 __attribute__((ext_vector_type(8)));
typedef unsigned short u16;

__device__ __forceinline__ unsigned short f2bf(float f) {
    unsigned int u = __float_as_uint(f);
    u += 0x7fffu + ((u >> 16) & 1u);   // round-to-nearest-even
    return (unsigned short)(u >> 16);
}

__global__ void zero_count_kernel(unsigned int* count) { *count = 0u; }

// ---------------- prep (fused): compute-node list + packed meta + W->bf16
//                  transpose + history copy.
// For each compute node (list slot p known at insertion): writes
//   list2[p] = {nid, e0, deg, 0}
//   emeta[p*16+j] = src | rel<<27   (j<min(deg,16); else 0xFFFFFFFF)
// so the gemm kernel starts with ONE coalesced load instead of the
// count->list->ptr->idx dependent chain.
__global__ __launch_bounds__(256) void prep_kernel(
        const float* __restrict__ W,
        const int* __restrict__ hmap, const float* __restrict__ hbuf,
        const int* __restrict__ ptr, const int* __restrict__ idx,
        const int* __restrict__ ety,
        unsigned short* __restrict__ Wt,
        int4* __restrict__ list2, unsigned* __restrict__ emeta,
        unsigned int* __restrict__ count,
        float* __restrict__ out, int NN, int WE) {
    int gid = blockIdx.x * blockDim.x + threadIdx.x;

    // compact list of compute nodes (wave-aggregated atomics). No early
    // returns above this point: all lanes must reach the ballot.
    {
        bool active = (gid < NN) && (hmap[gid] == -1);
        unsigned long long mask = __ballot(active);
        if (mask) {
            int lane   = threadIdx.x & 63;
            int leader = __ffsll((unsigned long long)mask) - 1;
            unsigned base = 0;
            if (lane == leader) base = atomicAdd(count, (unsigned)__popcll(mask));
            base = __shfl(base, leader, 64);
            if (active) {
                int off = __popcll(mask & ((1ull << lane) - 1ull));
                int p   = (int)base + off;
                int e0  = ptr[gid], e1 = ptr[gid + 1];
                int d   = e1 - e0;
                list2[p] = int4{gid, e0, d, 0};
                #pragma unroll
                for (int j = 0; j < 16; ++j) {
                    unsigned m = 0xFFFFFFFFu;
                    if (j < d) {
                        int e = e0 + j;
                        m = ((unsigned)idx[e]) | (((unsigned)ety[e]) << 27);
                    }
                    emeta[(size_t)p * 16 + j] = m;
                }
            }
        }
    }

    // per (node, f32x4-chunk): history-row copy to both output halves
    int n = gid >> 5;           // node
    int q = gid & 31;           // f32x4 index within 128-float row
    if (n < NN) {
        if (hmap[n] != -1) {
            f32x4 v = ((const f32x4*)hbuf)[(size_t)n * 32 + q];
            f32x4* o = (f32x4*)out;
            o[(size_t)n * 32 + q] = v;
            o[(size_t)NN * 32 + (size_t)n * 32 + q] = v;
        }
    }

    // W[r][k][c] -> Wt[c][r*128+k] in bf16
    if (gid < WE) {
        int r   = gid >> 14;      // / (128*128)
        int rem = gid & 16383;
        int k   = rem >> 7;       // / 128
        int c   = rem & 127;
        Wt[(size_t)c * K_TOTAL + r * IN_C + k] = f2bf(W[gid]);
    }
}

// ---------------- fused gather + bf16 MFMA GEMM, short-latency-chain version
// Start-of-block: one coalesced emeta load (1 KB/block, no dependences),
// metas distributed via intra-wave shfl (no LDS, no barrier). 2 barriers
// total in the common path (was 4).
__global__ __launch_bounds__(256, 4) void gemm_kernel(
        const float* __restrict__ x,
        const int* __restrict__ idx,
        const int* __restrict__ ety,
        const unsigned short* __restrict__ Wt,
        const int4* __restrict__ list2,
        const unsigned* __restrict__ emeta,
        const unsigned int* __restrict__ count,
        float* __restrict__ out, int NN) {
    __shared__ u16      S[TILE_M * SRB];      // 33024 B, bf16 staged A-tile
    __shared__ int      nids[TILE_M];
    __shared__ int      e0s[TILE_M];
    __shared__ int      degs[TILE_M];
    __shared__ float    invdeg[TILE_M];
    __shared__ unsigned meta_x[256];          // extension path (deg>16) only

    unsigned int cnt = *count;
    int rowbase = blockIdx.x * TILE_M;
    if (rowbase >= (int)cnt) return;          // uniform exit, before any barrier

    int t = threadIdx.x;
    int n = t >> 4;            // node slot 0..15
    int c = t & 15;            // 8-float channel chunk 0..15
    int lane = t & 63;

    // hop 1: coalesced meta load; emeta[(rowbase+n)*16 + c] == emeta[rowbase*16+t]
    bool vrow = (rowbase + n) < (int)cnt;
    unsigned mymeta = vrow ? emeta[(size_t)rowbase * 16 + t] : 0xFFFFFFFFu;

    // independent: per-tile node info into LDS (consumed after B1)
    if (t < TILE_M) {
        int nid = -1, e0 = 0, d = 0; float idg = 0.f;
        if (rowbase + t < (int)cnt) {
            int4 L = list2[rowbase + t];
            nid = L.x; e0 = L.y; d = L.z;
            idg = (d > 0) ? 1.0f / (float)d : 0.f;
        }
        nids[t] = nid; e0s[t] = e0; degs[t] = d; invdeg[t] = idg;
    }

    // distribute the 16 metas of node n across its 16 threads (intra-wave)
    unsigned mm[16];
    #pragma unroll
    for (int j = 0; j < 16; ++j)
        mm[j] = __shfl(mymeta, (lane & 48) | j, 64);

    int offs[16];   // element offset of this thread's chunk in x
    int rel[16];    // relation id, 31 = inactive (one-hot never matches)
    #pragma unroll
    for (int j = 0; j < 16; ++j) {
        unsigned m = mm[j];
        bool valid = (m != 0xFFFFFFFFu);
        int src = valid ? (int)(m & 0x07FFFFFFu) : 0;
        rel[j]  = valid ? (int)(m >> 27) : 31;
        offs[j] = src * IN_C;
    }

    // per-thread accumulator: 8 relations x 8 channels (64 VGPRs)
    f32x4 alo[NREL], ahi[NREL];
    #pragma unroll
    for (int r = 0; r < NREL; ++r) { alo[r] = f32x4{0,0,0,0}; ahi[r] = f32x4{0,0,0,0}; }

    const float* xc = x + c * 8;   // channel-chunk base

    // hop 2: gather, 4-edge batches, double-buffered (8 edges in flight)
    {
        f32x4 blo[4], bhi[4];
        #pragma unroll
        for (int u = 0; u < 4; ++u) {
            const f32x4* p = (const f32x4*)(xc + offs[u]);
            blo[u] = p[0]; bhi[u] = p[1];
        }
        #pragma unroll
        for (int b = 0; b < 4; ++b) {
            f32x4 nlo[4], nhi[4];
            if (b < 3) {
                #pragma unroll
                for (int u = 0; u < 4; ++u) {
                    const f32x4* p = (const f32x4*)(xc + offs[(b + 1) * 4 + u]);
                    nlo[u] = p[0]; nhi[u] = p[1];
                }
            }
            #pragma unroll
            for (int u = 0; u < 4; ++u) {
                int r = rel[b * 4 + u];
                #pragma unroll
                for (int rr = 0; rr < NREL; ++rr) {       // branchless one-hot
                    float mk = (r == rr) ? 1.0f : 0.0f;
                    alo[rr] += blo[u] * mk;
                    ahi[rr] += bhi[u] * mk;
                }
            }
            if (b < 3) {
                #pragma unroll
                for (int u = 0; u < 4; ++u) { blo[u] = nlo[u]; bhi[u] = nhi[u]; }
            }
        }
    }
    __syncthreads();   // B1: nids/degs/invdeg visible

    // rare general path: any node with deg > 16 (block-uniform branch)
    int md = 0;
    #pragma unroll
    for (int i = 0; i < TILE_M; ++i) md = max(md, degs[i]);
    if (md > TILE_M) {
        int nid_n = nids[n], deg_n = degs[n], e0_n = e0s[n];
        for (int jb = TILE_M; jb < md; jb += TILE_M) {
            {
                int j = jb + c;
                unsigned m = 0xFFFFFFFFu;
                if (nid_n >= 0 && j < deg_n) {
                    int e = e0_n + j;
                    m = ((unsigned)idx[e]) | (((unsigned)ety[e]) << 27);
                }
                meta_x[t] = m;
            }
            __syncthreads();
            uint4 q0 = *(const uint4*)(meta_x + (n << 4) + 0);
            uint4 q1 = *(const uint4*)(meta_x + (n << 4) + 4);
            uint4 q2 = *(const uint4*)(meta_x + (n << 4) + 8);
            uint4 q3 = *(const uint4*)(meta_x + (n << 4) + 12);
            unsigned mx[16] = {q0.x,q0.y,q0.z,q0.w, q1.x,q1.y,q1.z,q1.w,
                               q2.x,q2.y,q2.z,q2.w, q3.x,q3.y,q3.z,q3.w};
            #pragma unroll
            for (int j = 0; j < 16; ++j) {
                unsigned m = mx[j];
                bool valid = (m != 0xFFFFFFFFu);
                int src = valid ? (int)(m & 0x07FFFFFFu) : 0;
                int r   = valid ? (int)(m >> 27) : 31;
                const f32x4* p = (const f32x4*)(xc + src * IN_C);
                f32x4 lo = p[0], hi = p[1];
                #pragma unroll
                for (int rr = 0; rr < NREL; ++rr) {
                    float mk = (r == rr) ? 1.0f : 0.0f;
                    alo[rr] += lo * mk;
                    ahi[rr] += hi * mk;
                }
            }
            __syncthreads();
        }
    }

    // convert once to bf16, write S tile (write-once, no zeroing needed)
    {
        u16* srow = S + n * SRB + c * 8;
        #pragma unroll
        for (int rr = 0; rr < NREL; ++rr) {
            s16x8 pk;
            pk[0] = (short)f2bf(alo[rr][0]); pk[1] = (short)f2bf(alo[rr][1]);
            pk[2] = (short)f2bf(alo[rr][2]); pk[3] = (short)f2bf(alo[rr][3]);
            pk[4] = (short)f2bf(ahi[rr][0]); pk[5] = (short)f2bf(ahi[rr][1]);
            pk[6] = (short)f2bf(ahi[rr][2]); pk[7] = (short)f2bf(ahi[rr][3]);
            *(s16x8*)(srow + rr * IN_C) = pk;
        }
    }
    __syncthreads();   // B2: S ready

    // MFMA over K=1024
    int wave = t >> 6;
    int quad = lane >> 4, l16 = lane & 15;
    int chbase = wave * 32;                 // each wave owns 32 output channels
    const u16* arow  = S + l16 * SRB + quad * 8;
    const u16* bbase = Wt + (size_t)(chbase + l16) * K_TOTAL + quad * 8;

    f32x4 acc0 = {0.f,0.f,0.f,0.f};
    f32x4 acc1 = {0.f,0.f,0.f,0.f};
    #pragma unroll 8
    for (int ks = 0; ks < K_TOTAL; ks += 32) {
        s16x8 a  = *(const s16x8*)(arow + ks);
        s16x8 b0 = *(const s16x8*)(bbase + ks);
        s16x8 b1 = *(const s16x8*)(bbase + ks + 16 * K_TOTAL);
        union { s16x8 s; bf16x8 b; } ua, ub0, ub1;
        ua.s = a; ub0.s = b0; ub1.s = b1;
        acc0 = __builtin_amdgcn_mfma_f32_16x16x32_bf16(ua.b, ub0.b, acc0, 0, 0, 0);
        acc1 = __builtin_amdgcn_mfma_f32_16x16x32_bf16(ua.b, ub1.b, acc1, 0, 0, 0);
    }

    // epilogue: C/D layout col=lane&15, row=(lane>>4)*4+reg  (verified)
    size_t half = (size_t)NN * HID_C;
    #pragma unroll
    for (int v = 0; v < 4; ++v) {
        int rowl = quad * 4 + v;
        int onid = nids[rowl];
        if (onid < 0) continue;
        float s = invdeg[rowl];
        float v0 = acc0[v] * s;
        float v1 = acc1[v] * s;
        size_t o0 = (size_t)onid * HID_C + chbase + l16;
        out[o0]             = v0;
        out[o0 + 16]        = v1;
        out[o0 + half]      = v0;
        out[o0 + 16 + half] = v1;
    }
}

extern "C" void kernel_launch(void* const* d_in, const int* in_sizes, int n_in,
                              void* d_out, int out_size, void* d_ws, size_t ws_size,
                              hipStream_t stream) {
    const float* x    = (const float*)d_in[0];
    const float* W    = (const float*)d_in[1];
    const int*   ptr  = (const int*)d_in[2];
    const int*   idx  = (const int*)d_in[3];
    const int*   ety  = (const int*)d_in[4];
    const int*   hmap = (const int*)d_in[5];
    const float* hbuf = (const float*)d_in[6];
    int NN = in_sizes[5];          // 100000
    int WE = in_sizes[1];          // 8*128*128
    float* out = (float*)d_out;

    // workspace layout: count | list2(int4) | Wt(bf16) | emeta
    unsigned int* count = (unsigned int*)d_ws;
    int4* list2 = (int4*)((char*)d_ws + 256);
    size_t wt_off = 256 + (((size_t)NN * 16 + 4095) / 4096) * 4096;
    unsigned short* Wt = (unsigned short*)((char*)d_ws + wt_off);      // 256 KB
    size_t em_off = ((wt_off + (size_t)K_TOTAL * HID_C * 2 + 4095) / 4096) * 4096;
    unsigned* emeta = (unsigned*)((char*)d_ws + em_off);               // NN*16*4 B

    zero_count_kernel<<<1, 1, 0, stream>>>(count);

    long long tot = (long long)NN * 32;           // covers history copy
    if (tot < (long long)WE) tot = WE;
    prep_kernel<<<(int)((tot + 255) / 256), 256, 0, stream>>>(
        W, hmap, hbuf, ptr, idx, ety, Wt, list2, emeta, count, out, NN, WE);

    gemm_kernel<<<(NN + TILE_M - 1) / TILE_M, 256, 0, stream>>>(
        x, idx, ety, Wt, list2, emeta, count, out, NN);
}